// Round 10
// baseline (1431.734 us; speedup 1.0000x reference)
//
#include <hip/hip_runtime.h>
#include <math.h>

#define Tt 16384   // B*S tokens
#define Ss 4096
#define Bb 4
#define Hh 512
#define II 1024    // INNER
#define CHUNK 32
#define NCH 128    // S / CHUNK
#define SP 4098    // Ss + 2 halo rows per batch

typedef unsigned short ushort_t;
typedef unsigned int uint_t;
typedef __attribute__((ext_vector_type(8))) short bf16x8;
typedef __attribute__((ext_vector_type(4))) short bf16x4;
typedef __attribute__((ext_vector_type(4))) float f32x4;

__device__ __forceinline__ float sigm(float x) { return 1.0f / (1.0f + __expf(-x)); }
__device__ __forceinline__ float b2f(ushort_t h) { return __uint_as_float(((uint_t)h) << 16); }
__device__ __forceinline__ ushort_t f2b(float f) {
    uint_t u = __float_as_uint(f);
    return (ushort_t)((u + 0x7FFFu + ((u >> 16) & 1u)) >> 16);
}
__device__ __forceinline__ void stc(float* p, float v)    { *p = v; }
__device__ __forceinline__ void stc(ushort_t* p, float v) { *p = f2b(v); }
__device__ __forceinline__ float ldc1(const float* p)    { return *p; }
__device__ __forceinline__ float ldc1(const ushort_t* p) { return b2f(*p); }

// async global->LDS, 16B per lane; LDS dest = wave-uniform base + lane*16
__device__ __forceinline__ void gload16(const void* g, void* l) {
    __builtin_amdgcn_global_load_lds(
        (const __attribute__((address_space(1))) unsigned int*)g,
        (__attribute__((address_space(3))) unsigned int*)l,
        16, 0, 0);
}

// softplus -> clamped alpha / gate value (shared by scan1/scan3)
__device__ __forceinline__ void alpha_gate(float xv, float bgv, float xcv,
                                           float& ac, float& gv) {
    const float dt = (xv > 20.f) ? xv : log1pf(__expf(xv));
    const float alpha = sigm(0.1f * dt);
    ac = fminf(fmaxf(alpha, 0.01f), 0.99f);
    gv = (1.f - alpha) * bgv * xcv;
}

// ---------------------------------------------------------------------------
// MFMA bf16 GEMM, 128x128 tile, BK=32, 4 waves (each 64x64), m97 structure
// + LDS granule swizzle g' = g ^ ((row>>1)&3)  (pre-swizzled global source,
//   same swizzle on ds_read -- rule 21: both-sides-or-neither).
// C[m,n] = act( sum_k A[rowmap(m),k] * W[n,k] + bias[n] )
// amode: 0 linear; 1 flip-halo (xpad); 2 lin-halo (xpad); 3 conv-halo;
//        4 concat (A0 k<512, A1 k>=512)
// smode: 0 linear store, 1 halo store (c1pad)
// act: 0 none, 1 sigmoid, 2 silu (fuse==0 only)
// fuse: 0 none; 1 mcomb: g=sigm(v), C = g*C + (1-g)*e1[flip-row]  (C=m_fwd)
//       2 zmid : g=sigm(v), C = g*e0 + (1-g)*e1                   (C=zmidb)
// ---------------------------------------------------------------------------
__global__ __launch_bounds__(256) void mfma_gemm(
    const ushort_t* __restrict__ A, const ushort_t* __restrict__ A1, int lda,
    const ushort_t* __restrict__ W, int ldw,
    const float* __restrict__ bias,
    void* __restrict__ Cv, int ldc, int Nreal, int K,
    int amode, int act, int smode, int cbf16,
    int fuse, const ushort_t* __restrict__ e0, const ushort_t* __restrict__ e1)
{
    __shared__ __align__(16) ushort_t As[128 * 32];
    __shared__ __align__(16) ushort_t Bs[128 * 32];
    const int tid  = threadIdx.x;
    const int lane = tid & 63;
    const int wid  = tid >> 6;
    const int bm   = blockIdx.y * 128;
    const int bn   = blockIdx.x * 128;
    const int wr   = wid >> 1;
    const int wc   = wid & 1;

    // ---- staging: lane owns (row_local = lane>>2, LDS granule = lane&3);
    //      fetch global granule (lane&3) ^ ((row_local>>1)&3) ----
    const int colA = ((lane & 3) ^ ((lane >> 3) & 3)) * 8;
    long gA[2], gW[2];
    #pragma unroll
    for (int r = 0; r < 2; ++r) {
        const int rt = (r * 4 + wid) * 16 + (lane >> 2);   // tile row 0..127
        const int t  = bm + rt;
        const int b  = t >> 12;
        const int s  = t & (Ss - 1);
        long rowoff;
        if (amode == 0)      rowoff = (long)t * lda;
        else if (amode == 1) { const int sf = (s < 2048) ? (2047 - s) : s;
                               rowoff = (long)(b * SP + sf + 1) * 512; }
        else if (amode == 2) rowoff = (long)(b * SP + s + 1) * 512;
        else if (amode == 3) rowoff = (long)(b * SP + s) * 512;
        else                 rowoff = (long)t * 512;
        gA[r] = rowoff + colA;
        gW[r] = (long)(bn + rt) * ldw + colA;
    }

    // ---- fragment reads: row = lane&15, want global granule lane>>4
    //      -> LDS granule (lane>>4) ^ ((row>>1)&3) ----
    const int kswz = ((lane >> 4) ^ ((lane >> 1) & 3)) * 8;
    const int aoff = (wr * 64 + (lane & 15)) * 32 + kswz;
    const int boff = (wc * 64 + (lane & 15)) * 32 + kswz;

    f32x4 acc[4][4] = {};

    for (int k0 = 0; k0 < K; k0 += 32) {
        const ushort_t* pA = A;
        long kadd = k0;
        if (amode == 4) { pA = (k0 < 512) ? A : A1; kadd = k0 & 511; }
        #pragma unroll
        for (int r = 0; r < 2; ++r) {
            gload16(pA + gA[r] + kadd, &As[(r * 4 + wid) * 512]);
            gload16(W + gW[r] + k0,    &Bs[(r * 4 + wid) * 512]);
        }
        __syncthreads();   // drains vmcnt before use

        bf16x8 af[4], bfr[4];
        #pragma unroll
        for (int mi = 0; mi < 4; ++mi) af[mi]  = *(const bf16x8*)&As[aoff + mi * 512];
        #pragma unroll
        for (int ni = 0; ni < 4; ++ni) bfr[ni] = *(const bf16x8*)&Bs[boff + ni * 512];
        #pragma unroll
        for (int mi = 0; mi < 4; ++mi)
            #pragma unroll
            for (int ni = 0; ni < 4; ++ni)
                acc[mi][ni] = __builtin_amdgcn_mfma_f32_16x16x32_bf16(
                    af[mi], bfr[ni], acc[mi][ni], 0, 0, 0);
        __syncthreads();   // before next-tile overwrite
    }

    // ---- epilogue: C/D layout col=lane&15, row=(lane>>4)*4+r ----
    float* Cf = (float*)Cv;
    ushort_t* Cb = (ushort_t*)Cv;
    #pragma unroll
    for (int mi = 0; mi < 4; ++mi) {
        const int row0 = bm + wr * 64 + mi * 16 + (lane >> 4) * 4;
        #pragma unroll
        for (int ni = 0; ni < 4; ++ni) {
            const int col = bn + wc * 64 + ni * 16 + (lane & 15);
            if (col < Nreal) {
                const float bv = bias ? bias[col] : 0.f;
                #pragma unroll
                for (int r = 0; r < 4; ++r) {
                    float v = acc[mi][ni][r] + bv;
                    const int t = row0 + r;
                    if (fuse == 0) {
                        if (act == 1) v = sigm(v);
                        else if (act == 2) v = v * sigm(v);
                        long crow;
                        if (smode == 1) { const int b = t >> 12, s = t & (Ss - 1);
                                          crow = (long)(b * SP + s + 1); }
                        else crow = t;
                        if (cbf16) Cb[crow * ldc + col] = f2b(v);
                        else       Cf[crow * ldc + col] = v;
                    } else {
                        const float g = sigm(v);
                        const long idx = (long)t * ldc + col;
                        if (fuse == 1) {   // m_comb in place over C=m_fwd
                            const int b = t >> 12, s = t & (Ss - 1);
                            const int sf = (s < 2048) ? (2047 - s) : s;
                            const float mb =
                                b2f(e1[((long)((b << 12) | sf) << 9) + col]);
                            Cb[idx] = f2b(g * b2f(Cb[idx]) + (1.f - g) * mb);
                        } else {           // zmid
                            Cb[idx] = f2b(g * b2f(e0[idx]) + (1.f - g) * b2f(e1[idx]));
                        }
                    }
                }
            }
        }
    }
}

// --------------------------- fused convert kernel --------------------------
// One launch converts x->xpad (halo) + all 13 weight tensors to bf16.
struct CvtP {
    const float* x;
    const float* src[13];   // 0..8 plain, 9..10 xproj, 11..12 fe
    ushort_t* xpad;
    ushort_t* dst[13];
};

__global__ __launch_bounds__(256) void cvt_all(CvtP p)
{
    const int blk = blockIdx.x;
    const int tid = threadIdx.x;
    if (blk < 4098) {                       // x -> xpad with zero halo rows
        const int idx = blk * 256 + tid;    // Bb*SP*64
        const int c8 = (idx & 63) * 8;
        const int sp = (idx >> 6) % SP;
        const int b  = idx / (64 * SP);
        bf16x8 v;
        if (sp == 0 || sp == SP - 1) {
            v = (bf16x8)0;
        } else {
            const float* q = p.x + ((long)(b * Ss + sp - 1)) * 512 + c8;
            #pragma unroll
            for (int j = 0; j < 8; ++j) v[j] = (short)f2b(q[j]);
        }
        *(bf16x8*)&p.xpad[((long)(b * SP + sp)) * 512 + c8] = v;
    } else if (blk < 10242) {               // 9 plain f32->bf16 segments
        int seg, off;
        if      (blk < 5122) { seg = 0; off = blk - 4098; }
        else if (blk < 6146) { seg = 1; off = blk - 5122; }
        else if (blk < 7170) { seg = 2; off = blk - 6146; }
        else if (blk < 8194) { seg = 3; off = blk - 7170; }
        else if (blk < 8706) { seg = 4; off = blk - 8194; }
        else if (blk < 9218) { seg = 5; off = blk - 8706; }
        else if (blk < 9730) { seg = 6; off = blk - 9218; }
        else if (blk < 9986) { seg = 7; off = blk - 9730; }
        else                 { seg = 8; off = blk - 9986; }
        const long e = (long)(off * 256 + tid) * 4;
        const float4 f = *(const float4*)&p.src[seg][e];
        bf16x4 v;
        v[0] = (short)f2b(f.x); v[1] = (short)f2b(f.y);
        v[2] = (short)f2b(f.z); v[3] = (short)f2b(f.w);
        *(bf16x4*)&p.dst[seg][e] = v;
    } else if (blk < 12546) {               // xproj: [1056][1024] -> [1152][1024]
        const int seg = (blk < 11394) ? 9 : 10;
        const int off = blk - ((blk < 11394) ? 10242 : 11394);
        const long e = (long)(off * 256 + tid) * 4;
        const int n = (int)(e >> 10);
        bf16x4 v = (bf16x4)0;
        if (n < 1056) {
            const float4 f = *(const float4*)&p.src[seg][e];
            v[0] = (short)f2b(f.x); v[1] = (short)f2b(f.y);
            v[2] = (short)f2b(f.z); v[3] = (short)f2b(f.w);
        }
        *(bf16x4*)&p.dst[seg][e] = v;
    } else {                                 // fe conv (512,512,3) -> [512][j*512+c]
        const int seg = (blk < 15618) ? 11 : 12;
        const int off = blk - ((blk < 15618) ? 12546 : 15618);
        const int idx = off * 256 + tid;     // 512*1536
        const int n = idx / 1536;
        const int rem = idx - n * 1536;
        const int j = rem >> 9;
        const int c = rem & 511;
        p.dst[seg][idx] = f2b(p.src[seg][((long)n * 512 + c) * 3 + j]);
    }
}

// zero the halo rows of c1pad (runs after mamba phase: c1pad overlays xz)
__global__ __launch_bounds__(256) void zero_halo(ushort_t* __restrict__ p)
{
    const int i = blockIdx.x * 256 + threadIdx.x;   // Bb*2*64 = 512
    const int c8 = (i & 63) * 8;
    const int h = (i >> 6) & 1;
    const int b = i >> 7;
    const long row = (long)b * SP + (h ? SP - 1 : 0);
    *(bf16x8*)&p[row * 512 + c8] = (bf16x8)0;
}

// --------------------------- elementwise kernels ---------------------------

__global__ __launch_bounds__(256) void dwconv_silu_k(
    const ushort_t* __restrict__ xz, const float* __restrict__ w,
    const float* __restrict__ bias, ushort_t* __restrict__ out)
{
    const int idx = blockIdx.x * 256 + threadIdx.x;   // Tt*II
    const int c = idx & (II - 1);
    const int t = idx >> 10;
    const int s = t & (Ss - 1);
    const long rb = (long)t * 2048;
    const float w0 = w[c * 4 + 0], w1 = w[c * 4 + 1], w2 = w[c * 4 + 2], w3 = w[c * 4 + 3];
    float sum = bias[c] + b2f(xz[rb + c]) * w3;
    if (s >= 1) sum += b2f(xz[rb - 2048 + c]) * w2;
    if (s >= 2) sum += b2f(xz[rb - 2 * 2048 + c]) * w1;
    if (s >= 3) sum += b2f(xz[rb - 3 * 2048 + c]) * w0;
    out[idx] = f2b(sum * sigm(sum));
}

__global__ __launch_bounds__(256) void bgcg_k(
    const ushort_t* __restrict__ xs, float* __restrict__ bg, float* __restrict__ cg)
{
    const int t = blockIdx.x * 256 + threadIdx.x;
    if (t >= Tt) return;
    const ushort_t* p = xs + (long)t * 1056;
    float sb = 0.f, sc = 0.f;
    #pragma unroll
    for (int i = 0; i < 16; ++i) { sb += b2f(p[i]); sc += b2f(p[16 + i]); }
    bg[t] = sigm(sb * (1.f / 16.f));
    cg[t] = sigm(sc * (1.f / 16.f));
}

// scan phase 1: recomputes alpha/gated from raw dtlin + xc + bg
__global__ __launch_bounds__(256) void scan1_k(
    const ushort_t* __restrict__ dt, const ushort_t* __restrict__ xc,
    const float* __restrict__ bg,
    float* __restrict__ ap, float* __restrict__ gs)
{
    const int idx = blockIdx.x * 256 + threadIdx.x;   // Bb*NCH*II
    const int c = idx & (II - 1);
    const int ch = (idx >> 10) & (NCH - 1);
    const int b = idx >> 17;
    const int t0 = b * Ss + ch * CHUNK;
    const long base = (long)t0 * II + c;
    float P = 1.f, h = 0.f;
    #pragma unroll 4
    for (int i = 0; i < CHUNK; ++i) {
        const long o = base + (long)i * II;
        float ac, gv;
        alpha_gate(b2f(dt[o]), bg[t0 + i], b2f(xc[o]), ac, gv);
        P *= ac;
        h = ac * h + gv;
    }
    ap[idx] = P;
    gs[idx] = h;
}

__global__ __launch_bounds__(256) void scan2_k(
    const float* __restrict__ ap, const float* __restrict__ gs, float* __restrict__ hin)
{
    const int idx = blockIdx.x * 256 + threadIdx.x;   // Bb*II
    if (idx >= Bb * II) return;
    const int c = idx & (II - 1);
    const int b = idx >> 10;
    float h = 0.f;
    for (int ch = 0; ch < NCH; ++ch) {
        const long j = ((long)(b * NCH + ch) << 10) + c;
        hin[j] = h;
        h = ap[j] * h + gs[j];
    }
}

// scan phase 3 + yfinal: replay chunk, y = (h*cg + D*xc)*silu(z), in place
__global__ __launch_bounds__(256) void scan3_k(
    ushort_t* __restrict__ dt, const ushort_t* __restrict__ xc,
    const float* __restrict__ bg, const float* __restrict__ hin,
    const float* __restrict__ cg, const float* __restrict__ D,
    const ushort_t* __restrict__ xz)
{
    const int idx = blockIdx.x * 256 + threadIdx.x;
    const int c = idx & (II - 1);
    const int ch = (idx >> 10) & (NCH - 1);
    const int b = idx >> 17;
    const int t0 = b * Ss + ch * CHUNK;
    const long base = (long)t0 * II + c;
    const float Dv = D[c];
    float h = hin[idx];
    #pragma unroll 4
    for (int i = 0; i < CHUNK; ++i) {
        const long o = base + (long)i * II;
        const int t = t0 + i;
        const float xcv = b2f(xc[o]);
        float ac, gv;
        alpha_gate(b2f(dt[o]), bg[t], xcv, ac, gv);
        h = ac * h + gv;
        const float y = h * cg[t] + Dv * xcv;
        const float z = b2f(xz[(long)t * 2048 + II + c]);
        dt[o] = f2b(y * (z * sigm(z)));
    }
}

// out = LN(a + r) * gamma + beta ; one wave per token, 512 features
template <typename TA, typename TO>
__global__ __launch_bounds__(256) void ln_k(
    const TA* __restrict__ a, const float* __restrict__ r,
    const float* __restrict__ gam, const float* __restrict__ bet, TO* __restrict__ out)
{
    const int lane = threadIdx.x & 63;
    const int wave = threadIdx.x >> 6;
    const int t = blockIdx.x * 4 + wave;
    const TA* pa = a + (long)t * Hh + lane * 8;
    const float* pr = r + (long)t * Hh + lane * 8;
    float v[8];
    float s = 0.f;
    #pragma unroll
    for (int j = 0; j < 8; ++j) { v[j] = ldc1(&pa[j]) + pr[j]; s += v[j]; }
    #pragma unroll
    for (int off = 32; off; off >>= 1) s += __shfl_xor(s, off);
    const float mean = s * (1.f / 512.f);
    float vs = 0.f;
    #pragma unroll
    for (int j = 0; j < 8; ++j) { const float d = v[j] - mean; vs += d * d; }
    #pragma unroll
    for (int off = 32; off; off >>= 1) vs += __shfl_xor(vs, off);
    const float inv = rsqrtf(vs * (1.f / 512.f) + 1e-5f);
    TO* po = out + (long)t * Hh + lane * 8;
    const float* pg = gam + lane * 8;
    const float* pb = bet + lane * 8;
    #pragma unroll
    for (int j = 0; j < 8; ++j) stc(&po[j], (v[j] - mean) * inv * pg[j] + pb[j]);
}

// --------------------------- host-side helpers -----------------------------

static inline void gemm(hipStream_t st, const ushort_t* A, const ushort_t* A1, int lda,
                        const ushort_t* W, int ldw, const float* bias,
                        void* C, int ldc, int Nreal, int PN, int K,
                        int amode, int act, int smode, int cbf16,
                        int fuse = 0, const ushort_t* e0 = nullptr,
                        const ushort_t* e1 = nullptr)
{
    dim3 g(PN / 128, Tt / 128);
    mfma_gemm<<<g, 256, 0, st>>>(A, A1, lda, W, ldw, bias, C, ldc, Nreal, K,
                                 amode, act, smode, cbf16, fuse, e0, e1);
}

static void mamba_block(hipStream_t st, const ushort_t* xpad, int amode_in,
                        const ushort_t* w_in, const float* conv_w, const float* conv_b,
                        const ushort_t* w_xp, const ushort_t* w_dt, const float* dt_b,
                        const float* Dp, const ushort_t* w_out,
                        ushort_t* xz, ushort_t* xc, ushort_t* xs, ushort_t* dtl,
                        float* ap, float* gs, float* hin, float* bg, float* cg,
                        ushort_t* mout)
{
    const int gEW = (Tt * II) / 256;
    gemm(st, xpad, nullptr, 512, w_in, 512, nullptr, xz, 2048, 2048, 2048, 512,
         amode_in, 0, 0, 1);
    dwconv_silu_k<<<gEW, 256, 0, st>>>(xz, conv_w, conv_b, xc);
    gemm(st, xc, nullptr, 1024, w_xp, 1024, nullptr, xs, 1056, 1056, 1152, 1024,
         0, 0, 0, 1);
    bgcg_k<<<Tt / 256, 256, 0, st>>>(xs, bg, cg);
    // raw dt_lin (bias applied) -> dtl; scans recompute alpha/gated on the fly
    gemm(st, xs + 32, nullptr, 1056, w_dt, 1024, dt_b, dtl, 1024, 1024, 1024, 1024,
         0, 0, 0, 1);
    scan1_k<<<(Bb * NCH * II) / 256, 256, 0, st>>>(dtl, xc, bg, ap, gs);
    scan2_k<<<(Bb * II) / 256, 256, 0, st>>>(ap, gs, hin);
    scan3_k<<<(Bb * NCH * II) / 256, 256, 0, st>>>(dtl, xc, bg, hin, cg, Dp, xz);
    gemm(st, dtl, nullptr, 1024, w_out, 1024, nullptr, mout, 512, 512, 512, 1024,
         0, 0, 0, 1);
}

extern "C" void kernel_launch(void* const* d_in, const int* in_sizes, int n_in,
                              void* d_out, int out_size, void* d_ws, size_t ws_size,
                              hipStream_t stream)
{
    const float* x       = (const float*)d_in[0];
    const float* ds_w    = (const float*)d_in[2];
    const float* ds_b    = (const float*)d_in[3];
    const float* gate_w  = (const float*)d_in[4];
    const float* gate_b  = (const float*)d_in[5];
    const float* mix_w   = (const float*)d_in[6];
    const float* mix_b   = (const float*)d_in[7];
    const float* ln_g    = (const float*)d_in[8];
    const float* ln_b    = (const float*)d_in[9];
    const float* fe_c1_w = (const float*)d_in[10];
    const float* fe_c1_b = (const float*)d_in[11];
    const float* fe_c2_w = (const float*)d_in[12];
    const float* fe_c2_b = (const float*)d_in[13];
    const float* fe_ln_g = (const float*)d_in[14];
    const float* fe_ln_b = (const float*)d_in[15];
    const float* f_in_w    = (const float*)d_in[16];
    const float* f_conv_w  = (const float*)d_in[17];
    const float* f_conv_b  = (const float*)d_in[18];
    const float* f_xproj_w = (const float*)d_in[19];
    const float* f_dt_w    = (const float*)d_in[20];
    const float* f_dt_b    = (const float*)d_in[21];
    const float* f_D       = (const float*)d_in[22];
    const float* f_out_w   = (const float*)d_in[23];
    const float* b_in_w    = (const float*)d_in[24];
    const float* b_conv_w  = (const float*)d_in[25];
    const float* b_conv_b  = (const float*)d_in[26];
    const float* b_xproj_w = (const float*)d_in[27];
    const float* b_dt_w    = (const float*)d_in[28];
    const float* b_dt_b    = (const float*)d_in[29];
    const float* b_D       = (const float*)d_in[30];
    const float* b_out_w   = (const float*)d_in[31];

    char* base = (char*)d_ws;
    // --- mamba-phase layout ---
    ushort_t* xz    = (ushort_t*)(base + 0L);           // Tt*2048 bf16
    ushort_t* xc    = (ushort_t*)(base + 67108864L);    // Tt*II bf16
    ushort_t* xs    = (ushort_t*)(base + 100663296L);   // Tt*1056 bf16
    ushort_t* dtl   = (ushort_t*)(base + 135266304L);   // Tt*II bf16 (dtlin -> y)
    float*    ap    = (float*)(base + 168820736L);
    float*    gs    = (float*)(base + 170917888L);
    float*    hin   = (float*)(base + 173015040L);
    float*    bg    = (float*)(base + 175112192L);
    float*    cg    = (float*)(base + 175177728L);
    ushort_t* m_fwd = (ushort_t*)(base + 175243264L);   // Tt*Hh bf16
    ushort_t* m_bwd = (ushort_t*)(base + 192020480L);   // Tt*Hh bf16
    ushort_t* xpad  = (ushort_t*)(base + 208797696L);   // Bb*SP*512 bf16
    // --- bf16 weights (persist) ---
    ushort_t* w_fin  = (ushort_t*)(base + 225583104L);  // 2048x512
    ushort_t* w_bin  = (ushort_t*)(base + 227680256L);
    ushort_t* w_fxp  = (ushort_t*)(base + 229777408L);  // 1152x1024 (padded)
    ushort_t* w_bxp  = (ushort_t*)(base + 232136704L);
    ushort_t* w_fdt  = (ushort_t*)(base + 234496000L);  // 1024x1024
    ushort_t* w_bdt  = (ushort_t*)(base + 236593152L);
    ushort_t* w_fout = (ushort_t*)(base + 238690304L);  // 512x1024
    ushort_t* w_bout = (ushort_t*)(base + 239738880L);
    ushort_t* w_ds   = (ushort_t*)(base + 240787456L);  // 512x512
    ushort_t* w_gate = (ushort_t*)(base + 241311744L);  // 512x1024
    ushort_t* w_mix  = (ushort_t*)(base + 242360320L);  // 512x512
    ushort_t* w_fc1  = (ushort_t*)(base + 242884608L);  // 512x1536 (reshaped)
    ushort_t* w_fc2  = (ushort_t*)(base + 244457472L);  // end 246,030,336
    // --- top-path overlays (mamba scratch dead by then) ---
    ushort_t* c1pad = (ushort_t*)(base + 0L);           // Bb*SP*512 bf16
    ushort_t* c2    = (ushort_t*)(base + 16785408L);    // Tt*Hh bf16
    ushort_t* fout  = (ushort_t*)(base + 33562624L);    // Tt*Hh bf16
    ushort_t* zmidb = (ushort_t*)(base + 50339840L);    // Tt*Hh bf16
    float*    zmix  = (float*)(base + 67117056L);       // Tt*Hh f32

    // 0. one fused convert launch: x->xpad + all weights -> bf16
    CvtP cp;
    cp.x = x; cp.xpad = xpad;
    cp.src[0] = f_in_w;  cp.dst[0] = w_fin;
    cp.src[1] = b_in_w;  cp.dst[1] = w_bin;
    cp.src[2] = f_dt_w;  cp.dst[2] = w_fdt;
    cp.src[3] = b_dt_w;  cp.dst[3] = w_bdt;
    cp.src[4] = f_out_w; cp.dst[4] = w_fout;
    cp.src[5] = b_out_w; cp.dst[5] = w_bout;
    cp.src[6] = gate_w;  cp.dst[6] = w_gate;
    cp.src[7] = ds_w;    cp.dst[7] = w_ds;
    cp.src[8] = mix_w;   cp.dst[8] = w_mix;
    cp.src[9]  = f_xproj_w; cp.dst[9]  = w_fxp;
    cp.src[10] = b_xproj_w; cp.dst[10] = w_bxp;
    cp.src[11] = fe_c1_w;   cp.dst[11] = w_fc1;
    cp.src[12] = fe_c2_w;   cp.dst[12] = w_fc2;
    cvt_all<<<18690, 256, 0, stream>>>(cp);

    // 1-2. mamba fwd (lin-halo) / bwd (flip-halo)
    mamba_block(stream, xpad, 2, w_fin, f_conv_w, f_conv_b, w_fxp, w_fdt, f_dt_b,
                f_D, w_fout, xz, xc, xs, dtl, ap, gs, hin, bg, cg, m_fwd);
    mamba_block(stream, xpad, 1, w_bin, b_conv_w, b_conv_b, w_bxp, w_bdt, b_dt_b,
                b_D, w_bout, xz, xc, xs, dtl, ap, gs, hin, bg, cg, m_bwd);

    // 3. feature path: c1 = silu(conv3(x)) into halo layout; c2 = conv3(c1); LN
    zero_halo<<<2, 256, 0, stream>>>(c1pad);
    gemm(stream, xpad, nullptr, 512, w_fc1, 1536, fe_c1_b, c1pad, 512, 512, 512, 1536,
         3, 2, 1, 1);
    gemm(stream, c1pad, nullptr, 512, w_fc2, 1536, fe_c2_b, c2, 512, 512, 512, 1536,
         3, 0, 0, 1);
    ln_k<ushort_t, ushort_t><<<Tt / 4, 256, 0, stream>>>(c2, x, fe_ln_g, fe_ln_b, fout);

    // 4. ds GEMM fused with mcomb: m_fwd <- sigm(x@ds_w+b)*m_fwd + (1-.)*m_bwd[flip]
    gemm(stream, xpad, nullptr, 512, w_ds, 512, ds_b, m_fwd, 512, 512, 512, 512,
         2, 0, 0, 1, /*fuse=*/1, nullptr, m_bwd);

    // 5. gate GEMM fused with zmid: zmidb <- sigm([mc,fo]@gate_w+b)*mc + (1-.)*fo
    gemm(stream, m_fwd, fout, 512, w_gate, 1024, gate_b, zmidb, 512, 512, 512, 1024,
         4, 0, 0, 1, /*fuse=*/2, m_fwd, fout);

    // 6. z = z @ mix_w^T + mix_b  (f32 out)
    gemm(stream, zmidb, nullptr, 512, w_mix, 512, mix_b, zmix, 512, 512, 512, 512,
         0, 0, 0, 0);

    // 7. out = LN(z + x)
    ln_k<float, float><<<Tt / 4, 256, 0, stream>>>(zmix, x, ln_g, ln_b, (float*)d_out);
}

// Round 13
// 1297.571 us; speedup vs baseline: 1.1034x; 1.1034x over previous
//
#include <hip/hip_runtime.h>
#include <math.h>

#define Tt 16384   // B*S tokens
#define Ss 4096
#define Bb 4
#define Hh 512
#define II 1024    // INNER
#define CHUNK 32
#define NCH 128    // S / CHUNK
#define SP 4098    // Ss + 2 halo rows per batch

typedef unsigned short ushort_t;
typedef unsigned int uint_t;
typedef __attribute__((ext_vector_type(8))) short bf16x8;
typedef __attribute__((ext_vector_type(4))) short bf16x4;
typedef __attribute__((ext_vector_type(4))) float f32x4;

__device__ __forceinline__ float sigm(float x) { return 1.0f / (1.0f + __expf(-x)); }
__device__ __forceinline__ float b2f(ushort_t h) { return __uint_as_float(((uint_t)h) << 16); }
__device__ __forceinline__ ushort_t f2b(float f) {
    uint_t u = __float_as_uint(f);
    return (ushort_t)((u + 0x7FFFu + ((u >> 16) & 1u)) >> 16);
}
__device__ __forceinline__ void stc(float* p, float v)    { *p = v; }
__device__ __forceinline__ void stc(ushort_t* p, float v) { *p = f2b(v); }
__device__ __forceinline__ float ldc1(const float* p)    { return *p; }
__device__ __forceinline__ float ldc1(const ushort_t* p) { return b2f(*p); }

// async global->LDS, 16B per lane; LDS dest = wave-uniform base + lane*16
__device__ __forceinline__ void gload16(const void* g, void* l) {
    __builtin_amdgcn_global_load_lds(
        (const __attribute__((address_space(1))) unsigned int*)g,
        (__attribute__((address_space(3))) unsigned int*)l,
        16, 0, 0);
}

// softplus -> clamped alpha / gate value (shared by scan1/scan3)
__device__ __forceinline__ void alpha_gate(float xv, float bgv, float xcv,
                                           float& ac, float& gv) {
    const float dt = (xv > 20.f) ? xv : log1pf(__expf(xv));
    const float alpha = sigm(0.1f * dt);
    ac = fminf(fmaxf(alpha, 0.01f), 0.99f);
    gv = (1.f - alpha) * bgv * xcv;
}

// ---------------------------------------------------------------------------
// MFMA bf16 GEMM, 128x128 tile, BK=32, 4 waves (each 64x64).
// R11 changes vs R10 (both inside this kernel only):
//  (a) minimum 2-phase prefetch pipeline: double-buffered LDS; per K-step
//      issue next tile's global_load_lds BEFORE current tile's ds_read+MFMA;
//      single __syncthreads() per step (its vmcnt(0) drain lands the prefetch
//      that overlapped the compute).  1 barrier/step instead of 2, loads
//      overlap MFMA.
//  (b) XCD-aware bijective block swizzle (nwg always %8==0):
//      each XCD takes contiguous by-rows -> A panels fetched once per XCD.
// + LDS granule swizzle g' = g ^ ((row>>1)&3) retained (conflicts == 0).
// C[m,n] = act( sum_k A[rowmap(m),k] * W[n,k] + bias[n] )
// amode: 0 linear; 1 flip-halo (xpad); 2 lin-halo (xpad); 3 conv-halo;
//        4 concat (A0 k<512, A1 k>=512)
// smode: 0 linear store, 1 halo store (c1pad)
// act: 0 none, 1 sigmoid, 2 silu (fuse==0 only)
// fuse: 0 none; 1 mcomb: g=sigm(v), C = g*C + (1-g)*e1[flip-row]  (C=m_fwd)
//       2 zmid : g=sigm(v), C = g*e0 + (1-g)*e1                   (C=zmidb)
// ---------------------------------------------------------------------------
__global__ __launch_bounds__(256) void mfma_gemm(
    const ushort_t* __restrict__ A, const ushort_t* __restrict__ A1, int lda,
    const ushort_t* __restrict__ W, int ldw,
    const float* __restrict__ bias,
    void* __restrict__ Cv, int ldc, int Nreal, int K,
    int amode, int act, int smode, int cbf16,
    int fuse, const ushort_t* __restrict__ e0, const ushort_t* __restrict__ e1)
{
    __shared__ __align__(16) ushort_t As[2][128 * 32];
    __shared__ __align__(16) ushort_t Bs[2][128 * 32];
    const int tid  = threadIdx.x;
    const int lane = tid & 63;
    const int wid  = tid >> 6;

    // ---- XCD-aware bijective swizzle: contiguous logical chunk per XCD ----
    int bid = blockIdx.y * gridDim.x + blockIdx.x;
    const int nwg = gridDim.x * gridDim.y;      // always multiple of 8
    bid = (bid & 7) * (nwg >> 3) + (bid >> 3);
    const int bm = (bid / gridDim.x) * 128;
    const int bn = (bid % gridDim.x) * 128;

    const int wr = wid >> 1;
    const int wc = wid & 1;

    // ---- staging: lane owns (row_local = lane>>2, LDS granule = lane&3);
    //      fetch global granule (lane&3) ^ ((row_local>>1)&3) ----
    const int colA = ((lane & 3) ^ ((lane >> 3) & 3)) * 8;
    long gA[2], gW[2];
    #pragma unroll
    for (int r = 0; r < 2; ++r) {
        const int rt = (r * 4 + wid) * 16 + (lane >> 2);   // tile row 0..127
        const int t  = bm + rt;
        const int b  = t >> 12;
        const int s  = t & (Ss - 1);
        long rowoff;
        if (amode == 0)      rowoff = (long)t * lda;
        else if (amode == 1) { const int sf = (s < 2048) ? (2047 - s) : s;
                               rowoff = (long)(b * SP + sf + 1) * 512; }
        else if (amode == 2) rowoff = (long)(b * SP + s + 1) * 512;
        else if (amode == 3) rowoff = (long)(b * SP + s) * 512;
        else                 rowoff = (long)t * 512;
        gA[r] = rowoff + colA;
        gW[r] = (long)(bn + rt) * ldw + colA;
    }

    auto STAGE = [&](int bsel, int k0) {
        const ushort_t* pA = A;
        long kadd = k0;
        if (amode == 4) { pA = (k0 < 512) ? A : A1; kadd = k0 & 511; }
        #pragma unroll
        for (int r = 0; r < 2; ++r) {
            gload16(pA + gA[r] + kadd, &As[bsel][(r * 4 + wid) * 512]);
            gload16(W + gW[r] + k0,    &Bs[bsel][(r * 4 + wid) * 512]);
        }
    };

    // ---- fragment reads: row = lane&15, want global granule lane>>4
    //      -> LDS granule (lane>>4) ^ ((row>>1)&3) ----
    const int kswz = ((lane >> 4) ^ ((lane >> 1) & 3)) * 8;
    const int aoff = (wr * 64 + (lane & 15)) * 32 + kswz;
    const int boff = (wc * 64 + (lane & 15)) * 32 + kswz;

    f32x4 acc[4][4] = {};
    const int nt = K >> 5;

    STAGE(0, 0);
    __syncthreads();                    // tile 0 landed
    for (int kt = 0; kt < nt; ++kt) {
        const int cur = kt & 1;
        if (kt + 1 < nt) STAGE(cur ^ 1, (kt + 1) << 5);   // prefetch overlaps MFMA

        bf16x8 af[4], bfr[4];
        #pragma unroll
        for (int mi = 0; mi < 4; ++mi) af[mi]  = *(const bf16x8*)&As[cur][aoff + mi * 512];
        #pragma unroll
        for (int ni = 0; ni < 4; ++ni) bfr[ni] = *(const bf16x8*)&Bs[cur][boff + ni * 512];
        #pragma unroll
        for (int mi = 0; mi < 4; ++mi)
            #pragma unroll
            for (int ni = 0; ni < 4; ++ni)
                acc[mi][ni] = __builtin_amdgcn_mfma_f32_16x16x32_bf16(
                    af[mi], bfr[ni], acc[mi][ni], 0, 0, 0);

        __syncthreads();   // drains prefetch (vmcnt0) + protects buffer reuse
    }

    // ---- epilogue: C/D layout col=lane&15, row=(lane>>4)*4+r ----
    float* Cf = (float*)Cv;
    ushort_t* Cb = (ushort_t*)Cv;
    #pragma unroll
    for (int mi = 0; mi < 4; ++mi) {
        const int row0 = bm + wr * 64 + mi * 16 + (lane >> 4) * 4;
        #pragma unroll
        for (int ni = 0; ni < 4; ++ni) {
            const int col = bn + wc * 64 + ni * 16 + (lane & 15);
            if (col < Nreal) {
                const float bv = bias ? bias[col] : 0.f;
                #pragma unroll
                for (int r = 0; r < 4; ++r) {
                    float v = acc[mi][ni][r] + bv;
                    const int t = row0 + r;
                    if (fuse == 0) {
                        if (act == 1) v = sigm(v);
                        else if (act == 2) v = v * sigm(v);
                        long crow;
                        if (smode == 1) { const int b = t >> 12, s = t & (Ss - 1);
                                          crow = (long)(b * SP + s + 1); }
                        else crow = t;
                        if (cbf16) Cb[crow * ldc + col] = f2b(v);
                        else       Cf[crow * ldc + col] = v;
                    } else {
                        const float g = sigm(v);
                        const long idx = (long)t * ldc + col;
                        if (fuse == 1) {   // m_comb in place over C=m_fwd
                            const int b = t >> 12, s = t & (Ss - 1);
                            const int sf = (s < 2048) ? (2047 - s) : s;
                            const float mb =
                                b2f(e1[((long)((b << 12) | sf) << 9) + col]);
                            Cb[idx] = f2b(g * b2f(Cb[idx]) + (1.f - g) * mb);
                        } else {           // zmid
                            Cb[idx] = f2b(g * b2f(e0[idx]) + (1.f - g) * b2f(e1[idx]));
                        }
                    }
                }
            }
        }
    }
}

// --------------------------- fused convert kernel --------------------------
// One launch converts x->xpad (halo) + all 13 weight tensors to bf16.
struct CvtP {
    const float* x;
    const float* src[13];   // 0..8 plain, 9..10 xproj, 11..12 fe
    ushort_t* xpad;
    ushort_t* dst[13];
};

__global__ __launch_bounds__(256) void cvt_all(CvtP p)
{
    const int blk = blockIdx.x;
    const int tid = threadIdx.x;
    if (blk < 4098) {                       // x -> xpad with zero halo rows
        const int idx = blk * 256 + tid;    // Bb*SP*64
        const int c8 = (idx & 63) * 8;
        const int sp = (idx >> 6) % SP;
        const int b  = idx / (64 * SP);
        bf16x8 v;
        if (sp == 0 || sp == SP - 1) {
            v = (bf16x8)0;
        } else {
            const float* q = p.x + ((long)(b * Ss + sp - 1)) * 512 + c8;
            #pragma unroll
            for (int j = 0; j < 8; ++j) v[j] = (short)f2b(q[j]);
        }
        *(bf16x8*)&p.xpad[((long)(b * SP + sp)) * 512 + c8] = v;
    } else if (blk < 10242) {               // 9 plain f32->bf16 segments
        int seg, off;
        if      (blk < 5122) { seg = 0; off = blk - 4098; }
        else if (blk < 6146) { seg = 1; off = blk - 5122; }
        else if (blk < 7170) { seg = 2; off = blk - 6146; }
        else if (blk < 8194) { seg = 3; off = blk - 7170; }
        else if (blk < 8706) { seg = 4; off = blk - 8194; }
        else if (blk < 9218) { seg = 5; off = blk - 8706; }
        else if (blk < 9730) { seg = 6; off = blk - 9218; }
        else if (blk < 9986) { seg = 7; off = blk - 9730; }
        else                 { seg = 8; off = blk - 9986; }
        const long e = (long)(off * 256 + tid) * 4;
        const float4 f = *(const float4*)&p.src[seg][e];
        bf16x4 v;
        v[0] = (short)f2b(f.x); v[1] = (short)f2b(f.y);
        v[2] = (short)f2b(f.z); v[3] = (short)f2b(f.w);
        *(bf16x4*)&p.dst[seg][e] = v;
    } else if (blk < 12546) {               // xproj: [1056][1024] -> [1152][1024]
        const int seg = (blk < 11394) ? 9 : 10;
        const int off = blk - ((blk < 11394) ? 10242 : 11394);
        const long e = (long)(off * 256 + tid) * 4;
        const int n = (int)(e >> 10);
        bf16x4 v = (bf16x4)0;
        if (n < 1056) {
            const float4 f = *(const float4*)&p.src[seg][e];
            v[0] = (short)f2b(f.x); v[1] = (short)f2b(f.y);
            v[2] = (short)f2b(f.z); v[3] = (short)f2b(f.w);
        }
        *(bf16x4*)&p.dst[seg][e] = v;
    } else {                                 // fe conv (512,512,3) -> [512][j*512+c]
        const int seg = (blk < 15618) ? 11 : 12;
        const int off = blk - ((blk < 15618) ? 12546 : 15618);
        const int idx = off * 256 + tid;     // 512*1536
        const int n = idx / 1536;
        const int rem = idx - n * 1536;
        const int j = rem >> 9;
        const int c = rem & 511;
        p.dst[seg][idx] = f2b(p.src[seg][((long)n * 512 + c) * 3 + j]);
    }
}

// zero the halo rows of c1pad (runs after mamba phase: c1pad overlays xz)
__global__ __launch_bounds__(256) void zero_halo(ushort_t* __restrict__ p)
{
    const int i = blockIdx.x * 256 + threadIdx.x;   // Bb*2*64 = 512
    const int c8 = (i & 63) * 8;
    const int h = (i >> 6) & 1;
    const int b = i >> 7;
    const long row = (long)b * SP + (h ? SP - 1 : 0);
    *(bf16x8*)&p[row * 512 + c8] = (bf16x8)0;
}

// --------------------------- elementwise kernels ---------------------------

__global__ __launch_bounds__(256) void dwconv_silu_k(
    const ushort_t* __restrict__ xz, const float* __restrict__ w,
    const float* __restrict__ bias, ushort_t* __restrict__ out)
{
    const int idx = blockIdx.x * 256 + threadIdx.x;   // Tt*II
    const int c = idx & (II - 1);
    const int t = idx >> 10;
    const int s = t & (Ss - 1);
    const long rb = (long)t * 2048;
    const float w0 = w[c * 4 + 0], w1 = w[c * 4 + 1], w2 = w[c * 4 + 2], w3 = w[c * 4 + 3];
    float sum = bias[c] + b2f(xz[rb + c]) * w3;
    if (s >= 1) sum += b2f(xz[rb - 2048 + c]) * w2;
    if (s >= 2) sum += b2f(xz[rb - 2 * 2048 + c]) * w1;
    if (s >= 3) sum += b2f(xz[rb - 3 * 2048 + c]) * w0;
    out[idx] = f2b(sum * sigm(sum));
}

__global__ __launch_bounds__(256) void bgcg_k(
    const ushort_t* __restrict__ xs, float* __restrict__ bg, float* __restrict__ cg)
{
    const int t = blockIdx.x * 256 + threadIdx.x;
    if (t >= Tt) return;
    const ushort_t* p = xs + (long)t * 1056;
    float sb = 0.f, sc = 0.f;
    #pragma unroll
    for (int i = 0; i < 16; ++i) { sb += b2f(p[i]); sc += b2f(p[16 + i]); }
    bg[t] = sigm(sb * (1.f / 16.f));
    cg[t] = sigm(sc * (1.f / 16.f));
}

// scan phase 1: recomputes alpha/gated from raw dtlin + xc + bg
__global__ __launch_bounds__(256) void scan1_k(
    const ushort_t* __restrict__ dt, const ushort_t* __restrict__ xc,
    const float* __restrict__ bg,
    float* __restrict__ ap, float* __restrict__ gs)
{
    const int idx = blockIdx.x * 256 + threadIdx.x;   // Bb*NCH*II
    const int c = idx & (II - 1);
    const int ch = (idx >> 10) & (NCH - 1);
    const int b = idx >> 17;
    const int t0 = b * Ss + ch * CHUNK;
    const long base = (long)t0 * II + c;
    float P = 1.f, h = 0.f;
    #pragma unroll 4
    for (int i = 0; i < CHUNK; ++i) {
        const long o = base + (long)i * II;
        float ac, gv;
        alpha_gate(b2f(dt[o]), bg[t0 + i], b2f(xc[o]), ac, gv);
        P *= ac;
        h = ac * h + gv;
    }
    ap[idx] = P;
    gs[idx] = h;
}

__global__ __launch_bounds__(256) void scan2_k(
    const float* __restrict__ ap, const float* __restrict__ gs, float* __restrict__ hin)
{
    const int idx = blockIdx.x * 256 + threadIdx.x;   // Bb*II
    if (idx >= Bb * II) return;
    const int c = idx & (II - 1);
    const int b = idx >> 10;
    float h = 0.f;
    for (int ch = 0; ch < NCH; ++ch) {
        const long j = ((long)(b * NCH + ch) << 10) + c;
        hin[j] = h;
        h = ap[j] * h + gs[j];
    }
}

// scan phase 3 + yfinal: replay chunk, y = (h*cg + D*xc)*silu(z), in place
__global__ __launch_bounds__(256) void scan3_k(
    ushort_t* __restrict__ dt, const ushort_t* __restrict__ xc,
    const float* __restrict__ bg, const float* __restrict__ hin,
    const float* __restrict__ cg, const float* __restrict__ D,
    const ushort_t* __restrict__ xz)
{
    const int idx = blockIdx.x * 256 + threadIdx.x;
    const int c = idx & (II - 1);
    const int ch = (idx >> 10) & (NCH - 1);
    const int b = idx >> 17;
    const int t0 = b * Ss + ch * CHUNK;
    const long base = (long)t0 * II + c;
    const float Dv = D[c];
    float h = hin[idx];
    #pragma unroll 4
    for (int i = 0; i < CHUNK; ++i) {
        const long o = base + (long)i * II;
        const int t = t0 + i;
        const float xcv = b2f(xc[o]);
        float ac, gv;
        alpha_gate(b2f(dt[o]), bg[t], xcv, ac, gv);
        h = ac * h + gv;
        const float y = h * cg[t] + Dv * xcv;
        const float z = b2f(xz[(long)t * 2048 + II + c]);
        dt[o] = f2b(y * (z * sigm(z)));
    }
}

// out = LN(a + r) * gamma + beta ; one wave per token, 512 features
template <typename TA, typename TO>
__global__ __launch_bounds__(256) void ln_k(
    const TA* __restrict__ a, const float* __restrict__ r,
    const float* __restrict__ gam, const float* __restrict__ bet, TO* __restrict__ out)
{
    const int lane = threadIdx.x & 63;
    const int wave = threadIdx.x >> 6;
    const int t = blockIdx.x * 4 + wave;
    const TA* pa = a + (long)t * Hh + lane * 8;
    const float* pr = r + (long)t * Hh + lane * 8;
    float v[8];
    float s = 0.f;
    #pragma unroll
    for (int j = 0; j < 8; ++j) { v[j] = ldc1(&pa[j]) + pr[j]; s += v[j]; }
    #pragma unroll
    for (int off = 32; off; off >>= 1) s += __shfl_xor(s, off);
    const float mean = s * (1.f / 512.f);
    float vs = 0.f;
    #pragma unroll
    for (int j = 0; j < 8; ++j) { const float d = v[j] - mean; vs += d * d; }
    #pragma unroll
    for (int off = 32; off; off >>= 1) vs += __shfl_xor(vs, off);
    const float inv = rsqrtf(vs * (1.f / 512.f) + 1e-5f);
    TO* po = out + (long)t * Hh + lane * 8;
    const float* pg = gam + lane * 8;
    const float* pb = bet + lane * 8;
    #pragma unroll
    for (int j = 0; j < 8; ++j) stc(&po[j], (v[j] - mean) * inv * pg[j] + pb[j]);
}

// --------------------------- host-side helpers -----------------------------

static inline void gemm(hipStream_t st, const ushort_t* A, const ushort_t* A1, int lda,
                        const ushort_t* W, int ldw, const float* bias,
                        void* C, int ldc, int Nreal, int PN, int K,
                        int amode, int act, int smode, int cbf16,
                        int fuse = 0, const ushort_t* e0 = nullptr,
                        const ushort_t* e1 = nullptr)
{
    dim3 g(PN / 128, Tt / 128);
    mfma_gemm<<<g, 256, 0, st>>>(A, A1, lda, W, ldw, bias, C, ldc, Nreal, K,
                                 amode, act, smode, cbf16, fuse, e0, e1);
}

static void mamba_block(hipStream_t st, const ushort_t* xpad, int amode_in,
                        const ushort_t* w_in, const float* conv_w, const float* conv_b,
                        const ushort_t* w_xp, const ushort_t* w_dt, const float* dt_b,
                        const float* Dp, const ushort_t* w_out,
                        ushort_t* xz, ushort_t* xc, ushort_t* xs, ushort_t* dtl,
                        float* ap, float* gs, float* hin, float* bg, float* cg,
                        ushort_t* mout)
{
    const int gEW = (Tt * II) / 256;
    gemm(st, xpad, nullptr, 512, w_in, 512, nullptr, xz, 2048, 2048, 2048, 512,
         amode_in, 0, 0, 1);
    dwconv_silu_k<<<gEW, 256, 0, st>>>(xz, conv_w, conv_b, xc);
    gemm(st, xc, nullptr, 1024, w_xp, 1024, nullptr, xs, 1056, 1056, 1152, 1024,
         0, 0, 0, 1);
    bgcg_k<<<Tt / 256, 256, 0, st>>>(xs, bg, cg);
    // raw dt_lin (bias applied) -> dtl; scans recompute alpha/gated on the fly
    gemm(st, xs + 32, nullptr, 1056, w_dt, 1024, dt_b, dtl, 1024, 1024, 1024, 1024,
         0, 0, 0, 1);
    scan1_k<<<(Bb * NCH * II) / 256, 256, 0, st>>>(dtl, xc, bg, ap, gs);
    scan2_k<<<(Bb * II) / 256, 256, 0, st>>>(ap, gs, hin);
    scan3_k<<<(Bb * NCH * II) / 256, 256, 0, st>>>(dtl, xc, bg, hin, cg, Dp, xz);
    gemm(st, dtl, nullptr, 1024, w_out, 1024, nullptr, mout, 512, 512, 512, 1024,
         0, 0, 0, 1);
}

extern "C" void kernel_launch(void* const* d_in, const int* in_sizes, int n_in,
                              void* d_out, int out_size, void* d_ws, size_t ws_size,
                              hipStream_t stream)
{
    const float* x       = (const float*)d_in[0];
    const float* ds_w    = (const float*)d_in[2];
    const float* ds_b    = (const float*)d_in[3];
    const float* gate_w  = (const float*)d_in[4];
    const float* gate_b  = (const float*)d_in[5];
    const float* mix_w   = (const float*)d_in[6];
    const float* mix_b   = (const float*)d_in[7];
    const float* ln_g    = (const float*)d_in[8];
    const float* ln_b    = (const float*)d_in[9];
    const float* fe_c1_w = (const float*)d_in[10];
    const float* fe_c1_b = (const float*)d_in[11];
    const float* fe_c2_w = (const float*)d_in[12];
    const float* fe_c2_b = (const float*)d_in[13];
    const float* fe_ln_g = (const float*)d_in[14];
    const float* fe_ln_b = (const float*)d_in[15];
    const float* f_in_w    = (const float*)d_in[16];
    const float* f_conv_w  = (const float*)d_in[17];
    const float* f_conv_b  = (const float*)d_in[18];
    const float* f_xproj_w = (const float*)d_in[19];
    const float* f_dt_w    = (const float*)d_in[20];
    const float* f_dt_b    = (const float*)d_in[21];
    const float* f_D       = (const float*)d_in[22];
    const float* f_out_w   = (const float*)d_in[23];
    const float* b_in_w    = (const float*)d_in[24];
    const float* b_conv_w  = (const float*)d_in[25];
    const float* b_conv_b  = (const float*)d_in[26];
    const float* b_xproj_w = (const float*)d_in[27];
    const float* b_dt_w    = (const float*)d_in[28];
    const float* b_dt_b    = (const float*)d_in[29];
    const float* b_D       = (const float*)d_in[30];
    const float* b_out_w   = (const float*)d_in[31];

    char* base = (char*)d_ws;
    // --- mamba-phase layout ---
    ushort_t* xz    = (ushort_t*)(base + 0L);           // Tt*2048 bf16
    ushort_t* xc    = (ushort_t*)(base + 67108864L);    // Tt*II bf16
    ushort_t* xs    = (ushort_t*)(base + 100663296L);   // Tt*1056 bf16
    ushort_t* dtl   = (ushort_t*)(base + 135266304L);   // Tt*II bf16 (dtlin -> y)
    float*    ap    = (float*)(base + 168820736L);
    float*    gs    = (float*)(base + 170917888L);
    float*    hin   = (float*)(base + 173015040L);
    float*    bg    = (float*)(base + 175112192L);
    float*    cg    = (float*)(base + 175177728L);
    ushort_t* m_fwd = (ushort_t*)(base + 175243264L);   // Tt*Hh bf16
    ushort_t* m_bwd = (ushort_t*)(base + 192020480L);   // Tt*Hh bf16
    ushort_t* xpad  = (ushort_t*)(base + 208797696L);   // Bb*SP*512 bf16
    // --- bf16 weights (persist) ---
    ushort_t* w_fin  = (ushort_t*)(base + 225583104L);  // 2048x512
    ushort_t* w_bin  = (ushort_t*)(base + 227680256L);
    ushort_t* w_fxp  = (ushort_t*)(base + 229777408L);  // 1152x1024 (padded)
    ushort_t* w_bxp  = (ushort_t*)(base + 232136704L);
    ushort_t* w_fdt  = (ushort_t*)(base + 234496000L);  // 1024x1024
    ushort_t* w_bdt  = (ushort_t*)(base + 236593152L);
    ushort_t* w_fout = (ushort_t*)(base + 238690304L);  // 512x1024
    ushort_t* w_bout = (ushort_t*)(base + 239738880L);
    ushort_t* w_ds   = (ushort_t*)(base + 240787456L);  // 512x512
    ushort_t* w_gate = (ushort_t*)(base + 241311744L);  // 512x1024
    ushort_t* w_mix  = (ushort_t*)(base + 242360320L);  // 512x512
    ushort_t* w_fc1  = (ushort_t*)(base + 242884608L);  // 512x1536 (reshaped)
    ushort_t* w_fc2  = (ushort_t*)(base + 244457472L);  // end 246,030,336
    // --- top-path overlays (mamba scratch dead by then) ---
    ushort_t* c1pad = (ushort_t*)(base + 0L);           // Bb*SP*512 bf16
    ushort_t* c2    = (ushort_t*)(base + 16785408L);    // Tt*Hh bf16
    ushort_t* fout  = (ushort_t*)(base + 33562624L);    // Tt*Hh bf16
    ushort_t* zmidb = (ushort_t*)(base + 50339840L);    // Tt*Hh bf16
    float*    zmix  = (float*)(base + 67117056L);       // Tt*Hh f32

    // 0. one fused convert launch: x->xpad + all weights -> bf16
    CvtP cp;
    cp.x = x; cp.xpad = xpad;
    cp.src[0] = f_in_w;  cp.dst[0] = w_fin;
    cp.src[1] = b_in_w;  cp.dst[1] = w_bin;
    cp.src[2] = f_dt_w;  cp.dst[2] = w_fdt;
    cp.src[3] = b_dt_w;  cp.dst[3] = w_bdt;
    cp.src[4] = f_out_w; cp.dst[4] = w_fout;
    cp.src[5] = b_out_w; cp.dst[5] = w_bout;
    cp.src[6] = gate_w;  cp.dst[6] = w_gate;
    cp.src[7] = ds_w;    cp.dst[7] = w_ds;
    cp.src[8] = mix_w;   cp.dst[8] = w_mix;
    cp.src[9]  = f_xproj_w; cp.dst[9]  = w_fxp;
    cp.src[10] = b_xproj_w; cp.dst[10] = w_bxp;
    cp.src[11] = fe_c1_w;   cp.dst[11] = w_fc1;
    cp.src[12] = fe_c2_w;   cp.dst[12] = w_fc2;
    cvt_all<<<18690, 256, 0, stream>>>(cp);

    // 1-2. mamba fwd (lin-halo) / bwd (flip-halo)
    mamba_block(stream, xpad, 2, w_fin, f_conv_w, f_conv_b, w_fxp, w_fdt, f_dt_b,
                f_D, w_fout, xz, xc, xs, dtl, ap, gs, hin, bg, cg, m_fwd);
    mamba_block(stream, xpad, 1, w_bin, b_conv_w, b_conv_b, w_bxp, w_bdt, b_dt_b,
                b_D, w_bout, xz, xc, xs, dtl, ap, gs, hin, bg, cg, m_bwd);

    // 3. feature path: c1 = silu(conv3(x)) into halo layout; c2 = conv3(c1); LN
    zero_halo<<<2, 256, 0, stream>>>(c1pad);
    gemm(stream, xpad, nullptr, 512, w_fc1, 1536, fe_c1_b, c1pad, 512, 512, 512, 1536,
         3, 2, 1, 1);
    gemm(stream, c1pad, nullptr, 512, w_fc2, 1536, fe_c2_b, c2, 512, 512, 512, 1536,
         3, 0, 0, 1);
    ln_k<ushort_t, ushort_t><<<Tt / 4, 256, 0, stream>>>(c2, x, fe_ln_g, fe_ln_b, fout);

    // 4. ds GEMM fused with mcomb: m_fwd <- sigm(x@ds_w+b)*m_fwd + (1-.)*m_bwd[flip]
    gemm(stream, xpad, nullptr, 512, w_ds, 512, ds_b, m_fwd, 512, 512, 512, 512,
         2, 0, 0, 1, /*fuse=*/1, nullptr, m_bwd);

    // 5. gate GEMM fused with zmid: zmidb <- sigm([mc,fo]@gate_w+b)*mc + (1-.)*fo
    gemm(stream, m_fwd, fout, 512, w_gate, 1024, gate_b, zmidb, 512, 512, 512, 1024,
         4, 0, 0, 1, /*fuse=*/2, m_fwd, fout);

    // 6. z = z @ mix_w^T + mix_b  (f32 out)
    gemm(stream, zmidb, nullptr, 512, w_mix, 512, mix_b, zmix, 512, 512, 512, 512,
         0, 0, 0, 0);

    // 7. out = LN(z + x)
    ln_k<float, float><<<Tt / 4, 256, 0, stream>>>(zmix, x, ln_g, ln_b, (float*)d_out);
}